// Round 1
// 436.662 us; speedup vs baseline: 1.0233x; 1.0233x over previous
//
#include <hip/hip_runtime.h>

typedef __attribute__((ext_vector_type(8))) short short8;
typedef __attribute__((ext_vector_type(4))) float f32x4;
typedef __attribute__((ext_vector_type(4))) int i32x4;
typedef __attribute__((ext_vector_type(2))) unsigned u32x2;

#define LOG2E 1.44269504f

__device__ __forceinline__ short f2bf(float f) {
  unsigned u = __builtin_bit_cast(unsigned, f);
  u += 0x7fffu + ((u >> 16) & 1u);   // round-to-nearest-even
  return (short)(u >> 16);
}

// ---------------- fused prologue ----------------
// Per block (f, b): handles feat rows f*32..f*32+31 of batch b.
//  1. recompute w1 = W@a1, w2 = W@a2 per block (W is 256 KB, L2-hot; 512
//     blocks x 256 KB = 134 MB L2 reads ~ 4 us aggregate -- cheaper than a
//     serial 1-block kernel + extra dispatch boundary)
//  2. load feat tile once; Ax/Ay dot fused into the load; stage tile in LDS
//  3. pack MFMA B-fragments (bf16) from LDS
//  4. blocks (b==0, f<8) also pack WB
__global__ __launch_bounds__(256) void gat_pro(
    const float* __restrict__ feat, const float* __restrict__ W,
    const float* __restrict__ a1, const float* __restrict__ a2,
    short* __restrict__ featB, short* __restrict__ WB,
    float* __restrict__ AxL, float* __restrict__ AyL) {
  __shared__ __align__(16) float a1f[256], a2f[256];
  __shared__ __align__(16) float w1f[256], w2f[256];
  __shared__ __align__(16) float tile[32][260];   // pad: 260*4B = 65*16B, f4-aligned rows
  const int tid = threadIdx.x;
  const int f = blockIdx.x, b = blockIdx.y;

  a1f[tid] = a1[tid];
  a2f[tid] = a2[tid];
  __syncthreads();

  // w1/w2: identical arithmetic to the old gat_wvec (thread t -> row t of W)
  {
    float s1 = 0.f, s2 = 0.f;
    const float4* wr = (const float4*)(W + (size_t)tid * 256);
    for (int d0 = 0; d0 < 64; ++d0) {
      float4 v = wr[d0];
      s1 += v.x * a1f[d0 * 4] + v.y * a1f[d0 * 4 + 1] + v.z * a1f[d0 * 4 + 2] + v.w * a1f[d0 * 4 + 3];
      s2 += v.x * a2f[d0 * 4] + v.y * a2f[d0 * 4 + 1] + v.z * a2f[d0 * 4 + 2] + v.w * a2f[d0 * 4 + 3];
    }
    w1f[tid] = s1;
    w2f[tid] = s2;
  }
  __syncthreads();

  // feat tile load + fused Ax/Ay partial dots.
  // thread t: row r = t>>3, 8 float4 columns c4 = (t&7) + 8k.
  {
    const int r = tid >> 3, g8 = tid & 7;
    const float* frow = feat + ((size_t)(b * 4096 + f * 32 + r)) * 256;
    float s1 = 0.f, s2 = 0.f;
#pragma unroll
    for (int k = 0; k < 8; ++k) {
      const int c4 = g8 + 8 * k;
      float4 v = *(const float4*)(frow + c4 * 4);
      float4 u1 = *(const float4*)&w1f[c4 * 4];
      float4 u2 = *(const float4*)&w2f[c4 * 4];
      s1 += v.x * u1.x + v.y * u1.y + v.z * u1.z + v.w * u1.w;
      s2 += v.x * u2.x + v.y * u2.y + v.z * u2.z + v.w * u2.w;
      *(float4*)&tile[r][c4 * 4] = v;
    }
#pragma unroll
    for (int off = 4; off >= 1; off >>= 1) {
      s1 += __shfl_xor(s1, off);
      s2 += __shfl_xor(s2, off);
    }
    if (g8 == 0) {
      AxL[b * 4096 + f * 32 + r] = s1 * LOG2E;
      AyL[b * 4096 + f * 32 + r] = s2 * LOG2E;
    }
  }
  __syncthreads();

  // pack featB fragments (same layout as old packB):
  // dst[b][f][g][lane][j8] = bf16(tile[(lane>>4)*8 + j8][g*16 + (lane&15)])
  {
    const int g = tid >> 4, l15 = tid & 15;
    short* d = featB + (((size_t)((b * 128 + f) * 16 + g)) * 64) * 8;
#pragma unroll
    for (int q = 0; q < 4; ++q) {
      short8 v;
#pragma unroll
      for (int j8 = 0; j8 < 8; ++j8) v[j8] = f2bf(tile[q * 8 + j8][g * 16 + l15]);
      *(short8*)(d + (q * 16 + l15) * 8) = v;
    }
  }

  // fold W packing into 8 blocks of batch 0 (W L2-hot; ~32 KB each)
  if (b == 0 && f < 8) {
    const int g = tid >> 4, l15 = tid & 15;
    const float* s = W + ((size_t)f * 32) * 256 + g * 16 + l15;
    short* d = WB + (((size_t)(f * 16 + g)) * 64) * 8;
#pragma unroll
    for (int q = 0; q < 4; ++q) {
      short8 v;
#pragma unroll
      for (int j8 = 0; j8 < 8; ++j8) v[j8] = f2bf(s[(q * 8 + j8) * 256]);
      *(short8*)(d + (q * 16 + l15) * 8) = v;
    }
  }
}

// ---------------- per-batch max of AxL ----------------
__global__ void gat_max(const float* __restrict__ AxL, float* __restrict__ MbL) {
  __shared__ float red[256];
  const int b = blockIdx.x, tid = threadIdx.x;
  float m = -3.4e38f;
  for (int i = tid; i < 4096; i += 256) m = fmaxf(m, AxL[b * 4096 + i]);
  red[tid] = m;
  __syncthreads();
  for (int s = 128; s > 0; s >>= 1) {
    if (tid < s) red[tid] = fmaxf(red[tid], red[tid + s]);
    __syncthreads();
  }
  if (tid == 0) MbL[b] = red[0];
}

// -------- fused softmax(mask(lrelu(rank1)))@feat @W +ELU --------
// 16 super-chunks of 256 j; staggered j-window per block for HBM channel
// spread; P double-buffered in LDS; B operands are pre-packed MFMA
// fragments (L2-hot). One barrier per super-chunk. adj prefetched one
// super-chunk ahead (issued right after the barrier so it never has to be
// drained by the barrier's vmcnt(0)); axv issued FIRST so phase-1's first
// use proceeds at vmcnt(3) instead of a full drain.
__global__ __launch_bounds__(512, 4) void gat_attn(
    const short* __restrict__ featB,  // [4][128][16][64][8] bf16 fragments
    const int* __restrict__ adj,      // [4][4096][4096]
    const float* __restrict__ AxL, const float* __restrict__ AyL,
    const float* __restrict__ MbL,
    const short* __restrict__ WB,     // [8][16][64][8] bf16 fragments
    float* __restrict__ out)          // [4][4096][256] f32
{
  __shared__ short smem[16896];  // Pbuf[2][32][264]; later aliased as hbuf[32][264]

  const int tid = threadIdx.x;
  const int blk = blockIdx.x;
  const int x = blk & 7;
  const int b = x >> 1;                       // XCD-pinned batch
  const int it = ((blk >> 3) << 1) | (x & 1); // 0..127
  const int i0 = it << 5;
  const int scoff = (blk >> 3) & 15;          // staggered j-window start

  const int lane = tid & 63;
  const int aw = tid >> 6;                    // wave 0..7

  // --- P-producer: wave owns rows aw*4..aw*4+3; lane owns 4 j's ---
  float aLk[4], ddk[4];
#pragma unroll
  for (int k = 0; k < 4; ++k) {
    float ayL = AyL[b * 4096 + i0 + aw * 4 + k];
    float sL = ayL + MbL[b];
    float mrL = fmaxf(sL, 0.2f * sL);
    aLk[k] = ayL - mrL;
    ddk[k] = -0.8f * mrL;
  }
  const int* adjr = adj + ((size_t)(b * 4096 + i0 + aw * 4)) * 4096 + lane * 4;
  const float4* axp = (const float4*)(AxL + b * 4096) + lane;

  // --- MFMA role: wave = (row-group, col-group) ---
  const int w = aw;
  const int rowg = (w & 1) << 4;     // 0 / 16
  const int cgrp = (w >> 1) << 2;    // col-group base in 16-col units: 0,4,8,12
  const int l15 = lane & 15;
  const int q = lane >> 4;

  f32x4 acc[4], lac;
  lac = (f32x4){0.f, 0.f, 0.f, 0.f};
#pragma unroll
  for (int j = 0; j < 4; ++j) acc[j] = (f32x4){0.f, 0.f, 0.f, 0.f};

  short8 ones;
#pragma unroll
  for (int j = 0; j < 8; ++j) ones[j] = (short)0x3F80;  // bf16 1.0

  const short* fbb = featB + (size_t)b * 128 * 16 * 64 * 8 + lane * 8;

  i32x4 adv[4];
  float4 axv;
  {
    const int w0 = scoff;
    axv = axp[w0 * 64];
#pragma unroll
    for (int k = 0; k < 4; ++k)
      adv[k] = __builtin_nontemporal_load((const i32x4*)(adjr) + k * 1024 + w0 * 64);
  }

  for (int sc = 0; sc < 16; ++sc) {
    const int wsc = (scoff + sc) & 15;        // actual j-window this iteration
    const int pb = (sc & 1) * 8448;
    // ---- phase 1: 16 probs (4 rows x 4 j) -> Pbuf ----
    {
      const float* af = (const float*)&axv;
#pragma unroll
      for (int k = 0; k < 4; ++k) {
        unsigned pr[4];
#pragma unroll
        for (int u = 0; u < 4; ++u) {
          float v = af[u] + aLk[k];
          float uu = fmaxf(v, fmaf(0.2f, v, ddk[k]));
          unsigned ub = adv[k][u] > 0 ? __builtin_bit_cast(unsigned, uu) : 0xFF800000u;
          float p = __builtin_amdgcn_exp2f(__builtin_bit_cast(float, ub));
          pr[u] = __builtin_bit_cast(unsigned, p) + 0x8000u;
        }
        u32x2 pw;
        pw[0] = __builtin_amdgcn_perm(pr[1], pr[0], 0x07060302u);
        pw[1] = __builtin_amdgcn_perm(pr[3], pr[2], 0x07060302u);
        *(u32x2*)(smem + pb + (aw * 4 + k) * 264 + lane * 4) = pw;
      }
    }
    __syncthreads();

    // ---- prefetch next super-chunk's adj (contiguous 1 KB/instr) + Ax ----
    if (sc < 15) {
      const int wn = (scoff + sc + 1) & 15;
      axv = axp[wn * 64];
#pragma unroll
      for (int k = 0; k < 4; ++k)
        adv[k] = __builtin_nontemporal_load((const i32x4*)(adjr) + k * 1024 + wn * 64);
    }

    // ---- phase 2: 8 k-steps of MFMA; B frags coalesced L2-hot global loads ----
#pragma unroll
    for (int h = 0; h < 8; ++h) {
      const int f = wsc * 8 + h;
      const short* fb = fbb + (((size_t)f * 16 + cgrp) << 9);
      short8 a = *(const short8*)(smem + pb + (rowg + l15) * 264 + h * 32 + q * 8);
      lac = __builtin_amdgcn_mfma_f32_16x16x32_bf16(a, ones, lac, 0, 0, 0);
#pragma unroll
      for (int ct = 0; ct < 4; ++ct) {
        short8 bf = *(const short8*)(fb + (ct << 9));
        acc[ct] = __builtin_amdgcn_mfma_f32_16x16x32_bf16(a, bf, acc[ct], 0, 0, 0);
      }
    }
  }

  // lac[reg] = row-sum for row rowg + q*4 + reg (C/D layout)
  float linv[4];
#pragma unroll
  for (int reg = 0; reg < 4; ++reg) {
    float l = lac[reg];
    linv[reg] = l > 0.f ? 1.f / l : 0.f;
  }

  __syncthreads();   // all Pbuf reads done before aliasing smem as hbuf
  short* hbuf = smem;  // [32][264]
#pragma unroll
  for (int reg = 0; reg < 4; ++reg) {
    const int lr = rowg + q * 4 + reg;
#pragma unroll
    for (int ct = 0; ct < 4; ++ct)
      hbuf[lr * 264 + cgrp * 16 + ct * 16 + l15] = f2bf(acc[ct][reg] * linv[reg]);
  }
  __syncthreads();

  // ---- epilogue GEMM: (32x256) @ W, ELU, store; WB frags coalesced ----
  f32x4 ac2[4];
#pragma unroll
  for (int j = 0; j < 4; ++j) ac2[j] = (f32x4){0.f, 0.f, 0.f, 0.f};

  const short* wbb = WB + lane * 8;
#pragma unroll
  for (int f = 0; f < 8; ++f) {
    short8 a = *(const short8*)&hbuf[(rowg + l15) * 264 + f * 32 + q * 8];
    const short* wb = wbb + (((size_t)f * 16 + cgrp) << 9);
#pragma unroll
    for (int ct = 0; ct < 4; ++ct) {
      short8 bf = *(const short8*)(wb + (ct << 9));
      ac2[ct] = __builtin_amdgcn_mfma_f32_16x16x32_bf16(a, bf, ac2[ct], 0, 0, 0);
    }
  }

#pragma unroll
  for (int reg = 0; reg < 4; ++reg) {
    const int row = i0 + rowg + q * 4 + reg;
    float* orow = out + ((size_t)(b * 4096 + row)) * 256 + cgrp * 16 + l15;
#pragma unroll
    for (int ct = 0; ct < 4; ++ct) {
      float v = ac2[ct][reg];
      float o = v > 0.f ? v : (__builtin_amdgcn_exp2f(v * LOG2E) - 1.f);
      __builtin_nontemporal_store(o, orow + ct * 16);
    }
  }
}

extern "C" void kernel_launch(void* const* d_in, const int* in_sizes, int n_in,
                              void* d_out, int out_size, void* d_ws, size_t ws_size,
                              hipStream_t stream) {
  (void)in_sizes; (void)n_in; (void)out_size; (void)ws_size;
  const float* feat = (const float*)d_in[0];
  const int* adj = (const int*)d_in[1];
  const float* W = (const float*)d_in[2];
  const float* a1 = (const float*)d_in[3];
  const float* a2 = (const float*)d_in[4];
  float* out = (float*)d_out;

  char* ws = (char*)d_ws;
  short* featB   = (short*)ws;                     // 4*128*16*64*8*2 = 8,388,608 B
  short* WB      = (short*)(ws + 8388608);         // 131,072 B
  float* AxL     = (float*)(ws + 8519680);         // 64 KB
  float* AyL     = (float*)(ws + 8585216);         // 64 KB
  float* MbL     = (float*)(ws + 8650752);         // 16 B
  (void)ws_size;

  hipLaunchKernelGGL(gat_pro, dim3(128, 4), dim3(256), 0, stream, feat, W, a1, a2, featB, WB, AxL, AyL);
  hipLaunchKernelGGL(gat_max, dim3(4), dim3(256), 0, stream, AxL, MbL);
  hipLaunchKernelGGL(gat_attn, dim3(512), dim3(512), 0, stream, featB, adj, AxL, AyL, MbL, WB, out);
}

// Round 2
// 429.129 us; speedup vs baseline: 1.0413x; 1.0176x over previous
//
#include <hip/hip_runtime.h>

typedef __attribute__((ext_vector_type(8))) short short8;
typedef __attribute__((ext_vector_type(4))) float f32x4;
typedef __attribute__((ext_vector_type(4))) int i32x4;
typedef __attribute__((ext_vector_type(2))) unsigned u32x2;

#define LOG2E 1.44269504f

__device__ __forceinline__ short f2bf(float f) {
  unsigned u = __builtin_bit_cast(unsigned, f);
  u += 0x7fffu + ((u >> 16) & 1u);   // round-to-nearest-even
  return (short)(u >> 16);
}

// ---------------- fused prologue ----------------
// Per block (f, b): handles feat rows f*32..f*32+31 of batch b.
//  1. recompute w1 = W@a1, w2 = W@a2 per block (W L2-hot)
//  2. load feat tile once; Ax/Ay dot fused into the load; stage tile in LDS
//  3. pack MFMA B-fragments (bf16) from LDS
//  4. blocks (b==0, f<8) also pack WB
__global__ __launch_bounds__(256) void gat_pro(
    const float* __restrict__ feat, const float* __restrict__ W,
    const float* __restrict__ a1, const float* __restrict__ a2,
    short* __restrict__ featB, short* __restrict__ WB,
    float* __restrict__ AxL, float* __restrict__ AyL) {
  __shared__ __align__(16) float a1f[256], a2f[256];
  __shared__ __align__(16) float w1f[256], w2f[256];
  __shared__ __align__(16) float tile[32][260];
  const int tid = threadIdx.x;
  const int f = blockIdx.x, b = blockIdx.y;

  a1f[tid] = a1[tid];
  a2f[tid] = a2[tid];
  __syncthreads();

  {
    float s1 = 0.f, s2 = 0.f;
    const float4* wr = (const float4*)(W + (size_t)tid * 256);
    for (int d0 = 0; d0 < 64; ++d0) {
      float4 v = wr[d0];
      s1 += v.x * a1f[d0 * 4] + v.y * a1f[d0 * 4 + 1] + v.z * a1f[d0 * 4 + 2] + v.w * a1f[d0 * 4 + 3];
      s2 += v.x * a2f[d0 * 4] + v.y * a2f[d0 * 4 + 1] + v.z * a2f[d0 * 4 + 2] + v.w * a2f[d0 * 4 + 3];
    }
    w1f[tid] = s1;
    w2f[tid] = s2;
  }
  __syncthreads();

  {
    const int r = tid >> 3, g8 = tid & 7;
    const float* frow = feat + ((size_t)(b * 4096 + f * 32 + r)) * 256;
    float s1 = 0.f, s2 = 0.f;
#pragma unroll
    for (int k = 0; k < 8; ++k) {
      const int c4 = g8 + 8 * k;
      float4 v = *(const float4*)(frow + c4 * 4);
      float4 u1 = *(const float4*)&w1f[c4 * 4];
      float4 u2 = *(const float4*)&w2f[c4 * 4];
      s1 += v.x * u1.x + v.y * u1.y + v.z * u1.z + v.w * u1.w;
      s2 += v.x * u2.x + v.y * u2.y + v.z * u2.z + v.w * u2.w;
      *(float4*)&tile[r][c4 * 4] = v;
    }
#pragma unroll
    for (int off = 4; off >= 1; off >>= 1) {
      s1 += __shfl_xor(s1, off);
      s2 += __shfl_xor(s2, off);
    }
    if (g8 == 0) {
      AxL[b * 4096 + f * 32 + r] = s1 * LOG2E;
      AyL[b * 4096 + f * 32 + r] = s2 * LOG2E;
    }
  }
  __syncthreads();

  {
    const int g = tid >> 4, l15 = tid & 15;
    short* d = featB + (((size_t)((b * 128 + f) * 16 + g)) * 64) * 8;
#pragma unroll
    for (int q = 0; q < 4; ++q) {
      short8 v;
#pragma unroll
      for (int j8 = 0; j8 < 8; ++j8) v[j8] = f2bf(tile[q * 8 + j8][g * 16 + l15]);
      *(short8*)(d + (q * 16 + l15) * 8) = v;
    }
  }

  if (b == 0 && f < 8) {
    const int g = tid >> 4, l15 = tid & 15;
    const float* s = W + ((size_t)f * 32) * 256 + g * 16 + l15;
    short* d = WB + (((size_t)(f * 16 + g)) * 64) * 8;
#pragma unroll
    for (int q = 0; q < 4; ++q) {
      short8 v;
#pragma unroll
      for (int j8 = 0; j8 < 8; ++j8) v[j8] = f2bf(s[(q * 8 + j8) * 256]);
      *(short8*)(d + (q * 16 + l15) * 8) = v;
    }
  }
}

// -------- fused softmax(mask(lrelu(rank1)))@feat @W +ELU --------
// 64-row blocks: each wave owns TWO row-groups (rowg, rowg+32) and one
// col-group, so every featB B-fragment load feeds 2 MFMAs -> featB L2
// traffic per output row is halved vs the 32-row version (the modeled
// bottleneck: ~268 -> ~134 MB L2 reads per XCD). 16 super-chunks of 256 j,
// staggered start per block; P double-buffered (2x 64x264 shorts, 67.6 KB);
// one barrier per super-chunk; adj prefetched one super-chunk ahead.
// Per-batch AxL max computed in-block (replaces the gat_max kernel).
__global__ __launch_bounds__(512, 2) void gat_attn(
    const short* __restrict__ featB,  // [4][128][16][64][8] bf16 fragments
    const int* __restrict__ adj,      // [4][4096][4096]
    const float* __restrict__ AxL, const float* __restrict__ AyL,
    const short* __restrict__ WB,     // [8][16][64][8] bf16 fragments
    float* __restrict__ out)          // [4][4096][256] f32
{
  __shared__ short smem[33792];  // Pbuf[2][64][264]; later aliased as hbuf[64][264]
  __shared__ float mred[8];

  const int tid = threadIdx.x;
  const int blk = blockIdx.x;
  const int x = blk & 7;
  const int b = x >> 1;                       // XCD-pinned batch
  const int it = ((blk >> 3) << 1) | (x & 1); // 0..63
  const int i0 = it << 6;
  const int scoff = (blk >> 3) & 15;          // staggered j-window start

  const int lane = tid & 63;
  const int aw = tid >> 6;                    // wave 0..7

  // ---- per-batch max of AxL (was its own kernel) ----
  const float* axb = AxL + b * 4096;
  float mx = -3.4e38f;
  for (int i = tid; i < 4096; i += 512) mx = fmaxf(mx, axb[i]);
#pragma unroll
  for (int off = 32; off >= 1; off >>= 1) mx = fmaxf(mx, __shfl_xor(mx, off));
  if (lane == 0) mred[aw] = mx;
  __syncthreads();
  const float MbLb = fmaxf(fmaxf(fmaxf(mred[0], mred[1]), fmaxf(mred[2], mred[3])),
                           fmaxf(fmaxf(mred[4], mred[5]), fmaxf(mred[6], mred[7])));

  // --- P-producer: wave owns rows aw*8..aw*8+7; lane owns 4 j's ---
  float aLk[8], ddk[8];
#pragma unroll
  for (int k = 0; k < 8; ++k) {
    float ayL = AyL[b * 4096 + i0 + aw * 8 + k];
    float sL = ayL + MbLb;
    float mrL = fmaxf(sL, 0.2f * sL);
    aLk[k] = ayL - mrL;
    ddk[k] = -0.8f * mrL;
  }
  const int* adjr = adj + ((size_t)(b * 4096 + i0 + aw * 8)) * 4096 + lane * 4;
  const float4* axp = (const float4*)(AxL + b * 4096) + lane;

  // --- MFMA role: wave = (row-group pair, col-group) ---
  const int rowg = (aw & 1) << 4;    // 0/16; second group is +32
  const int cgrp = (aw >> 1) << 2;   // col-group base in 16-col units: 0,4,8,12
  const int l15 = lane & 15;
  const int q = lane >> 4;

  f32x4 acc[2][4], lac[2];
#pragma unroll
  for (int r = 0; r < 2; ++r) {
    lac[r] = (f32x4){0.f, 0.f, 0.f, 0.f};
#pragma unroll
    for (int j = 0; j < 4; ++j) acc[r][j] = (f32x4){0.f, 0.f, 0.f, 0.f};
  }

  short8 ones;
#pragma unroll
  for (int j = 0; j < 8; ++j) ones[j] = (short)0x3F80;  // bf16 1.0

  const short* fbb = featB + (size_t)b * 128 * 16 * 64 * 8 + lane * 8;

  i32x4 adv[8];
  float4 axv;
  {
    const int w0 = scoff;
    axv = axp[w0 * 64];
#pragma unroll
    for (int k = 0; k < 8; ++k)
      adv[k] = __builtin_nontemporal_load((const i32x4*)(adjr) + (size_t)k * 1024 + w0 * 64);
  }

  for (int sc = 0; sc < 16; ++sc) {
    const int wsc = (scoff + sc) & 15;        // actual j-window this iteration
    const int pb = (sc & 1) * 16896;
    // ---- phase 1: 32 probs (8 rows x 4 j) -> Pbuf ----
    {
      const float* af = (const float*)&axv;
#pragma unroll
      for (int k = 0; k < 8; ++k) {
        unsigned pr[4];
#pragma unroll
        for (int u = 0; u < 4; ++u) {
          float v = af[u] + aLk[k];
          float uu = fmaxf(v, fmaf(0.2f, v, ddk[k]));
          unsigned ub = adv[k][u] > 0 ? __builtin_bit_cast(unsigned, uu) : 0xFF800000u;
          float p = __builtin_amdgcn_exp2f(__builtin_bit_cast(float, ub));
          pr[u] = __builtin_bit_cast(unsigned, p) + 0x8000u;
        }
        u32x2 pw;
        pw[0] = __builtin_amdgcn_perm(pr[1], pr[0], 0x07060302u);
        pw[1] = __builtin_amdgcn_perm(pr[3], pr[2], 0x07060302u);
        *(u32x2*)(smem + pb + (aw * 8 + k) * 264 + lane * 4) = pw;
      }
    }
    __syncthreads();

    // ---- prefetch next super-chunk's adj (contiguous 1 KB/instr) + Ax ----
    if (sc < 15) {
      const int wn = (scoff + sc + 1) & 15;
      axv = axp[wn * 64];
#pragma unroll
      for (int k = 0; k < 8; ++k)
        adv[k] = __builtin_nontemporal_load((const i32x4*)(adjr) + (size_t)k * 1024 + wn * 64);
    }

    // ---- phase 2: 8 k-steps; each B fragment feeds both row-groups ----
#pragma unroll
    for (int h = 0; h < 8; ++h) {
      const int f = wsc * 8 + h;
      const short* fb = fbb + (((size_t)f * 16 + cgrp) << 9);
      short8 a0 = *(const short8*)(smem + pb + (rowg + l15) * 264 + h * 32 + q * 8);
      short8 a1 = *(const short8*)(smem + pb + (rowg + 32 + l15) * 264 + h * 32 + q * 8);
      lac[0] = __builtin_amdgcn_mfma_f32_16x16x32_bf16(a0, ones, lac[0], 0, 0, 0);
      lac[1] = __builtin_amdgcn_mfma_f32_16x16x32_bf16(a1, ones, lac[1], 0, 0, 0);
#pragma unroll
      for (int ct = 0; ct < 4; ++ct) {
        short8 bf = *(const short8*)(fb + (ct << 9));
        acc[0][ct] = __builtin_amdgcn_mfma_f32_16x16x32_bf16(a0, bf, acc[0][ct], 0, 0, 0);
        acc[1][ct] = __builtin_amdgcn_mfma_f32_16x16x32_bf16(a1, bf, acc[1][ct], 0, 0, 0);
      }
    }
  }

  // lac[r][reg] = row-sum for row rowg + r*32 + q*4 + reg (C/D layout)
  float linv[2][4];
#pragma unroll
  for (int r = 0; r < 2; ++r)
#pragma unroll
    for (int reg = 0; reg < 4; ++reg) {
      float l = lac[r][reg];
      linv[r][reg] = l > 0.f ? 1.f / l : 0.f;
    }

  __syncthreads();   // all Pbuf reads done before aliasing smem as hbuf
  short* hbuf = smem;  // [64][264]
#pragma unroll
  for (int r = 0; r < 2; ++r)
#pragma unroll
    for (int reg = 0; reg < 4; ++reg) {
      const int lr = rowg + r * 32 + q * 4 + reg;
#pragma unroll
      for (int ct = 0; ct < 4; ++ct)
        hbuf[lr * 264 + cgrp * 16 + ct * 16 + l15] = f2bf(acc[r][ct][reg] * linv[r][reg]);
    }
  __syncthreads();

  // ---- epilogue GEMM: (64x256) @ W, ELU, store; WB frags coalesced ----
  f32x4 ac2[2][4];
#pragma unroll
  for (int r = 0; r < 2; ++r)
#pragma unroll
    for (int j = 0; j < 4; ++j) ac2[r][j] = (f32x4){0.f, 0.f, 0.f, 0.f};

  const short* wbb = WB + lane * 8;
#pragma unroll
  for (int f = 0; f < 8; ++f) {
    short8 a0 = *(const short8*)&hbuf[(rowg + l15) * 264 + f * 32 + q * 8];
    short8 a1 = *(const short8*)&hbuf[(rowg + 32 + l15) * 264 + f * 32 + q * 8];
    const short* wb = wbb + (((size_t)f * 16 + cgrp) << 9);
#pragma unroll
    for (int ct = 0; ct < 4; ++ct) {
      short8 bf = *(const short8*)(wb + (ct << 9));
      ac2[0][ct] = __builtin_amdgcn_mfma_f32_16x16x32_bf16(a0, bf, ac2[0][ct], 0, 0, 0);
      ac2[1][ct] = __builtin_amdgcn_mfma_f32_16x16x32_bf16(a1, bf, ac2[1][ct], 0, 0, 0);
    }
  }

#pragma unroll
  for (int r = 0; r < 2; ++r)
#pragma unroll
    for (int reg = 0; reg < 4; ++reg) {
      const int row = i0 + rowg + r * 32 + q * 4 + reg;
      float* orow = out + ((size_t)(b * 4096 + row)) * 256 + cgrp * 16 + l15;
#pragma unroll
      for (int ct = 0; ct < 4; ++ct) {
        float v = ac2[r][ct][reg];
        float o = v > 0.f ? v : (__builtin_amdgcn_exp2f(v * LOG2E) - 1.f);
        __builtin_nontemporal_store(o, orow + ct * 16);
      }
    }
}

extern "C" void kernel_launch(void* const* d_in, const int* in_sizes, int n_in,
                              void* d_out, int out_size, void* d_ws, size_t ws_size,
                              hipStream_t stream) {
  (void)in_sizes; (void)n_in; (void)out_size; (void)ws_size;
  const float* feat = (const float*)d_in[0];
  const int* adj = (const int*)d_in[1];
  const float* W = (const float*)d_in[2];
  const float* a1 = (const float*)d_in[3];
  const float* a2 = (const float*)d_in[4];
  float* out = (float*)d_out;

  char* ws = (char*)d_ws;
  short* featB   = (short*)ws;                     // 4*128*16*64*8*2 = 8,388,608 B
  short* WB      = (short*)(ws + 8388608);         // 131,072 B
  float* AxL     = (float*)(ws + 8519680);         // 64 KB
  float* AyL     = (float*)(ws + 8585216);         // 64 KB

  hipLaunchKernelGGL(gat_pro, dim3(128, 4), dim3(256), 0, stream, feat, W, a1, a2, featB, WB, AxL, AyL);
  hipLaunchKernelGGL(gat_attn, dim3(256), dim3(512), 0, stream, featB, adj, AxL, AyL, WB, out);
}